// Round 1
// baseline (3881.577 us; speedup 1.0000x reference)
//
#include <hip/hip_runtime.h>
#include <hip/hip_bf16.h>

typedef unsigned int u32;
typedef unsigned short u16;

#define NEG (-10000.0f)

// ---------- helpers ----------
__device__ __forceinline__ float bf2f(u16 x){ return __uint_as_float(((u32)x) << 16); }
__device__ __forceinline__ u16 f2bf(float f){
    u32 u = __float_as_uint(f);
    u32 r = (u + 0x7fffu + ((u >> 16) & 1u)) >> 16;   // RNE
    return (u16)r;
}
__device__ __forceinline__ float sigm(float x){ return 1.0f / (1.0f + __expf(-x)); }
__device__ __forceinline__ float tanh_(float x){
    float e = __expf(2.0f * x);
    return 1.0f - 2.0f / (e + 1.0f);
}

// ---------- K0: swizzle W_hh (f32 -> bf16), layout [dir][q][g][r][e] ----------
// Wsw[dir*262144 + ((q*4+g)*256 + r)*8 + e] = W_hh_dir[(g*256+r)*256 + q*8 + e]
__global__ void k0_swizzle(const float* __restrict__ Whh_f,
                           const float* __restrict__ Whh_b,
                           u16* __restrict__ wsw){
    int idx = blockIdx.x * blockDim.x + threadIdx.x;
    if (idx >= 2 * 262144) return;
    int dir = idx >> 18;
    int rem = idx & 0x3FFFF;
    int e = rem & 7;
    int r = (rem >> 3) & 255;
    int g = (rem >> 11) & 3;
    int q = rem >> 13;
    const float* W = dir ? Whh_b : Whh_f;
    wsw[idx] = f2bf(W[(g * 256 + r) * 256 + q * 8 + e]);
}

// ---------- K1: input projection GEMM, fp32 tiled, X = emb@W_ih^T + b_ih + b_hh (bf16 out) ----------
__global__ __launch_bounds__(256) void k1_inproj(
    const int* __restrict__ sent, const float* __restrict__ emb,
    const float* __restrict__ Wih_f, const float* __restrict__ bih_f, const float* __restrict__ bhh_f,
    const float* __restrict__ Wih_b, const float* __restrict__ bih_b, const float* __restrict__ bhh_b,
    u16* __restrict__ X){
    int dir = blockIdx.z;
    const float* W  = dir ? Wih_b : Wih_f;
    const float* b1 = dir ? bih_b : bih_f;
    const float* b2 = dir ? bhh_b : bhh_f;
    u16* Xo = X + (size_t)dir * 8192 * 1024;

    __shared__ float As[16][68];
    __shared__ float Bs[16][68];

    int tid = threadIdx.x;
    int tx = tid & 15, ty = tid >> 4;
    int m0 = blockIdx.x * 64, n0 = blockIdx.y * 64;

    int lm = tid >> 2;        // 0..63
    int lk = (tid & 3) * 4;   // 0,4,8,12
    int sid = sent[m0 + lm];
    const float* arow = emb + (size_t)sid * 256;
    const float* brow = W + (size_t)(n0 + lm) * 256;

    float acc[4][4] = {};

    for (int k0 = 0; k0 < 256; k0 += 16){
        float4 av = *(const float4*)(arow + k0 + lk);
        float4 bv = *(const float4*)(brow + k0 + lk);
        __syncthreads();
        As[lk+0][lm]=av.x; As[lk+1][lm]=av.y; As[lk+2][lm]=av.z; As[lk+3][lm]=av.w;
        Bs[lk+0][lm]=bv.x; Bs[lk+1][lm]=bv.y; Bs[lk+2][lm]=bv.z; Bs[lk+3][lm]=bv.w;
        __syncthreads();
        #pragma unroll
        for (int kk = 0; kk < 16; kk++){
            float4 a = *(const float4*)&As[kk][ty * 4];
            float4 b = *(const float4*)&Bs[kk][tx * 4];
            acc[0][0]+=a.x*b.x; acc[0][1]+=a.x*b.y; acc[0][2]+=a.x*b.z; acc[0][3]+=a.x*b.w;
            acc[1][0]+=a.y*b.x; acc[1][1]+=a.y*b.y; acc[1][2]+=a.y*b.z; acc[1][3]+=a.y*b.w;
            acc[2][0]+=a.z*b.x; acc[2][1]+=a.z*b.y; acc[2][2]+=a.z*b.z; acc[2][3]+=a.z*b.w;
            acc[3][0]+=a.w*b.x; acc[3][1]+=a.w*b.y; acc[3][2]+=a.w*b.z; acc[3][3]+=a.w*b.w;
        }
    }

    #pragma unroll
    for (int i = 0; i < 4; i++){
        int m = m0 + ty * 4 + i;
        int n = n0 + tx * 4;
        ushort4 o;
        o.x = f2bf(acc[i][0] + b1[n+0] + b2[n+0]);
        o.y = f2bf(acc[i][1] + b1[n+1] + b2[n+1]);
        o.z = f2bf(acc[i][2] + b1[n+2] + b2[n+2]);
        o.w = f2bf(acc[i][3] + b1[n+3] + b2[n+3]);
        *(ushort4*)(Xo + (size_t)m * 1024 + n) = o;
    }
}

// ---------- K2: recurrent LSTM, one WG per (batch, dir), 256 threads ----------
__device__ __forceinline__ void gfma(float& acc, uint4 w, float4 ha, float4 hb){
    acc += __uint_as_float(w.x << 16)         * ha.x;
    acc += __uint_as_float(w.x & 0xFFFF0000u) * ha.y;
    acc += __uint_as_float(w.y << 16)         * ha.z;
    acc += __uint_as_float(w.y & 0xFFFF0000u) * ha.w;
    acc += __uint_as_float(w.z << 16)         * hb.x;
    acc += __uint_as_float(w.z & 0xFFFF0000u) * hb.y;
    acc += __uint_as_float(w.w << 16)         * hb.z;
    acc += __uint_as_float(w.w & 0xFFFF0000u) * hb.w;
}

__global__ __launch_bounds__(256) void k2_lstm(
    const u16* __restrict__ X, const u16* __restrict__ wsw,
    const float* __restrict__ h0, const float* __restrict__ c0,
    u16* __restrict__ HS){
    int b = blockIdx.x, dir = blockIdx.y;
    int r = threadIdx.x;
    __shared__ __align__(16) float hl[256];

    const u16* W  = wsw + (size_t)dir * 262144;
    const u16* Xd = X + (size_t)dir * 8192 * 1024 + (size_t)b * 256 * 1024;
    u16* HSo = HS + ((size_t)dir * 32 + b) * 256 * 256;

    float h = h0[(dir * 32 + b) * 256 + r];
    float c = c0[(dir * 32 + b) * 256 + r];
    hl[r] = h;
    __syncthreads();

    for (int s = 0; s < 256; s++){
        int tt = dir ? (255 - s) : s;
        const u16* xr = Xd + (size_t)tt * 1024;
        float a0 = bf2f(xr[r]);
        float a1 = bf2f(xr[256 + r]);
        float a2 = bf2f(xr[512 + r]);
        float a3 = bf2f(xr[768 + r]);

        #pragma unroll 4
        for (int q = 0; q < 32; q++){
            float4 ha = *(const float4*)&hl[q * 8];
            float4 hb = *(const float4*)&hl[q * 8 + 4];
            const u16* wq = W + (size_t)q * 8192 + (size_t)r * 8;
            uint4 w0 = *(const uint4*)(wq);
            uint4 w1 = *(const uint4*)(wq + 2048);
            uint4 w2 = *(const uint4*)(wq + 4096);
            uint4 w3 = *(const uint4*)(wq + 6144);
            gfma(a0, w0, ha, hb);
            gfma(a1, w1, ha, hb);
            gfma(a2, w2, ha, hb);
            gfma(a3, w3, ha, hb);
        }

        float ig = sigm(a0), fg = sigm(a1), gg = tanh_(a2), og = sigm(a3);
        c = fg * c + ig * gg;
        h = og * tanh_(c);

        __syncthreads();          // all lanes done reading old hl
        hl[r] = h;
        HSo[(size_t)tt * 256 + r] = f2bf(h);
        __syncthreads();          // new hl visible
    }
}

// ---------- K3: feats = concat(fwd,bwd) @ W_out^T + b_out ----------
__global__ __launch_bounds__(192) void k3_feats(
    const u16* __restrict__ HS, const float* __restrict__ Wout,
    const float* __restrict__ bout, float* __restrict__ feats){
    int bt = blockIdx.x;            // b*256 + t
    int b = bt >> 8, t = bt & 255;
    __shared__ float hcat[512];
    __shared__ float part[12][16];
    int tid = threadIdx.x;

    for (int i = tid; i < 512; i += 192){
        int d = i >> 8, k = i & 255;
        hcat[i] = bf2f(HS[((size_t)(d * 32 + b) * 256 + t) * 256 + k]);
    }
    __syncthreads();

    int n = tid >> 4, p = tid & 15;     // n 0..11, p 0..15
    float s = 0.0f;
    const float* wr = Wout + (size_t)n * 512 + p * 32;
    #pragma unroll
    for (int e = 0; e < 32; e++) s += hcat[p * 32 + e] * wr[e];
    part[n][p] = s;
    __syncthreads();

    if (tid < 12){
        float acc = bout[tid];
        #pragma unroll
        for (int p2 = 0; p2 < 16; p2++) acc += part[tid][p2];
        feats[(size_t)bt * 12 + tid] = acc;
    }
}

// ---------- K4: CRF forward (log Z) + gold score, per batch ----------
__global__ __launch_bounds__(192) void k4_crf(
    const float* __restrict__ feats, const float* __restrict__ trans,
    const int* __restrict__ tags, float* __restrict__ scores){
    int b = blockIdx.x;
    int tid = threadIdx.x;
    int i = tid >> 4, j = tid & 15;     // i 0..11, j 0..15 (j<12 active)
    bool act = (j < 12);

    __shared__ float fv[12];
    __shared__ float red[12];
    __shared__ float s_lz;
    __shared__ float gred[192];

    float tij = act ? trans[i * 12 + j] : NEG;
    if (tid < 12) fv[tid] = (tid == 0) ? 0.0f : NEG;   // START = idx 0
    __syncthreads();

    const float* fb = feats + (size_t)b * 256 * 12;

    for (int t = 0; t < 256; t++){
        float e = act ? (fv[j] + tij) : -3.0e38f;
        float m = e;
        #pragma unroll
        for (int off = 1; off < 16; off <<= 1) m = fmaxf(m, __shfl_xor(m, off, 16));
        float ex = act ? __expf(e - m) : 0.0f;
        float ss = ex;
        #pragma unroll
        for (int off = 1; off < 16; off <<= 1) ss += __shfl_xor(ss, off, 16);
        if (j == 0) red[i] = fb[t * 12 + i] + m + __logf(ss);
        __syncthreads();
        if (tid < 12) fv[tid] = red[tid];
        __syncthreads();
    }

    // log Z = lse_j(fv[j] + trans[STOP][j]), STOP = 1
    if (i == 0){
        float e = (j < 12) ? (fv[j] + trans[12 + j]) : -3.0e38f;
        float m = e;
        #pragma unroll
        for (int off = 1; off < 16; off <<= 1) m = fmaxf(m, __shfl_xor(m, off, 16));
        float ex = (j < 12) ? __expf(e - m) : 0.0f;
        float ss = ex;
        #pragma unroll
        for (int off = 1; off < 16; off <<= 1) ss += __shfl_xor(ss, off, 16);
        if (j == 0) s_lz = m + __logf(ss);
    }
    __syncthreads();

    // gold score
    const int* tg = tags + b * 256;
    float gsum = 0.0f;
    for (int t = tid; t < 256; t += 192){
        int cur = tg[t];
        int prev = (t == 0) ? 0 : tg[t - 1];
        gsum += fb[t * 12 + cur] + trans[cur * 12 + prev];
    }
    gred[tid] = gsum;
    __syncthreads();
    if (tid == 0){
        float g = 0.0f;
        for (int k = 0; k < 192; k++) g += gred[k];
        g += trans[12 + tg[255]];           // trans[STOP][last]
        scores[b] = s_lz - g;
    }
}

// ---------- K5: final reduce over batches ----------
__global__ void k5_final(const float* __restrict__ scores, float* __restrict__ out){
    int t = threadIdx.x;
    float v = scores[t];
    #pragma unroll
    for (int off = 16; off; off >>= 1) v += __shfl_xor(v, off, 32);
    if (t == 0) out[0] = v;
}

// ---------- launch ----------
extern "C" void kernel_launch(void* const* d_in, const int* in_sizes, int n_in,
                              void* d_out, int out_size, void* d_ws, size_t ws_size,
                              hipStream_t stream){
    const int*   sent  = (const int*)d_in[0];
    const int*   tags  = (const int*)d_in[1];
    // d_in[2] lengths: unused by reference
    const float* emb   = (const float*)d_in[3];
    const float* Wih_f = (const float*)d_in[4];
    const float* Whh_f = (const float*)d_in[5];
    const float* bih_f = (const float*)d_in[6];
    const float* bhh_f = (const float*)d_in[7];
    const float* Wih_b = (const float*)d_in[8];
    const float* Whh_b = (const float*)d_in[9];
    const float* bih_b = (const float*)d_in[10];
    const float* bhh_b = (const float*)d_in[11];
    const float* Wout  = (const float*)d_in[12];
    const float* bout  = (const float*)d_in[13];
    const float* trans = (const float*)d_in[14];
    const float* h0    = (const float*)d_in[15];
    const float* c0    = (const float*)d_in[16];

    char* ws = (char*)d_ws;
    u16*   X      = (u16*)(ws);                    // 2*8192*1024 bf16 = 32 MB
    u16*   HS     = (u16*)(ws + 33554432);         // 2*32*256*256 bf16 = 8 MB
    float* FEATS  = (float*)(ws + 41943040);       // 32*256*12 f32
    u16*   WSW    = (u16*)(ws + 42336256);         // 2*1024*256 bf16 = 1 MB
    float* SCORES = (float*)(ws + 43384832);       // 32 f32

    hipLaunchKernelGGL(k0_swizzle, dim3(2048), dim3(256), 0, stream, Whh_f, Whh_b, WSW);
    hipLaunchKernelGGL(k1_inproj, dim3(128, 16, 2), dim3(256), 0, stream,
                       sent, emb, Wih_f, bih_f, bhh_f, Wih_b, bih_b, bhh_b, X);
    hipLaunchKernelGGL(k2_lstm, dim3(32, 2), dim3(256), 0, stream, X, WSW, h0, c0, HS);
    hipLaunchKernelGGL(k3_feats, dim3(8192), dim3(192), 0, stream, HS, Wout, bout, FEATS);
    hipLaunchKernelGGL(k4_crf, dim3(32), dim3(192), 0, stream, FEATS, trans, tags, SCORES);
    hipLaunchKernelGGL(k5_final, dim3(1), dim3(32), 0, stream, SCORES, (float*)d_out);
}

// Round 2
// 1374.255 us; speedup vs baseline: 2.8245x; 2.8245x over previous
//
#include <hip/hip_runtime.h>
#include <hip/hip_bf16.h>

typedef unsigned int u32;
typedef unsigned short u16;

typedef __attribute__((ext_vector_type(8))) __bf16 bf16x8;
typedef __attribute__((ext_vector_type(4))) float f32x4;

#define NEG (-10000.0f)

// ---------- helpers ----------
__device__ __forceinline__ float bf2f(u16 x){ return __uint_as_float(((u32)x) << 16); }
__device__ __forceinline__ u16 f2bf(float f){
    u32 u = __float_as_uint(f);
    u32 r = (u + 0x7fffu + ((u >> 16) & 1u)) >> 16;   // RNE
    return (u16)r;
}
__device__ __forceinline__ float sigm(float x){ return 1.0f / (1.0f + __expf(-x)); }
__device__ __forceinline__ float tanh_(float x){
    float e = __expf(2.0f * x);
    return 1.0f - 2.0f / (e + 1.0f);
}

// ---------- K0: convert W_hh f32 -> bf16, same [1024][256] row-major layout ----------
__global__ void k0_convert(const float* __restrict__ Whh_f,
                           const float* __restrict__ Whh_b,
                           u16* __restrict__ wsw){
    int idx = blockIdx.x * blockDim.x + threadIdx.x;
    if (idx >= 2 * 262144) return;
    int dir = idx >> 18;
    const float* W = dir ? Whh_b : Whh_f;
    wsw[idx] = f2bf(W[idx & 0x3FFFF]);
}

// ---------- K_zero: zero the step flags ----------
__global__ void k_zero(int* __restrict__ flags){
    flags[threadIdx.x] = 0;
}

// ---------- K1: input projection GEMM, fp32 tiled, X = emb@W_ih^T + b_ih + b_hh (bf16 out) ----------
__global__ __launch_bounds__(256) void k1_inproj(
    const int* __restrict__ sent, const float* __restrict__ emb,
    const float* __restrict__ Wih_f, const float* __restrict__ bih_f, const float* __restrict__ bhh_f,
    const float* __restrict__ Wih_b, const float* __restrict__ bih_b, const float* __restrict__ bhh_b,
    u16* __restrict__ X){
    int dir = blockIdx.z;
    const float* W  = dir ? Wih_b : Wih_f;
    const float* b1 = dir ? bih_b : bih_f;
    const float* b2 = dir ? bhh_b : bhh_f;
    u16* Xo = X + (size_t)dir * 8192 * 1024;

    __shared__ float As[16][68];
    __shared__ float Bs[16][68];

    int tid = threadIdx.x;
    int tx = tid & 15, ty = tid >> 4;
    int m0 = blockIdx.x * 64, n0 = blockIdx.y * 64;

    int lm = tid >> 2;        // 0..63
    int lk = (tid & 3) * 4;   // 0,4,8,12
    int sid = sent[m0 + lm];
    const float* arow = emb + (size_t)sid * 256;
    const float* brow = W + (size_t)(n0 + lm) * 256;

    float acc[4][4] = {};

    for (int k0 = 0; k0 < 256; k0 += 16){
        float4 av = *(const float4*)(arow + k0 + lk);
        float4 bv = *(const float4*)(brow + k0 + lk);
        __syncthreads();
        As[lk+0][lm]=av.x; As[lk+1][lm]=av.y; As[lk+2][lm]=av.z; As[lk+3][lm]=av.w;
        Bs[lk+0][lm]=bv.x; Bs[lk+1][lm]=bv.y; Bs[lk+2][lm]=bv.z; Bs[lk+3][lm]=bv.w;
        __syncthreads();
        #pragma unroll
        for (int kk = 0; kk < 16; kk++){
            float4 a = *(const float4*)&As[kk][ty * 4];
            float4 b = *(const float4*)&Bs[kk][tx * 4];
            acc[0][0]+=a.x*b.x; acc[0][1]+=a.x*b.y; acc[0][2]+=a.x*b.z; acc[0][3]+=a.x*b.w;
            acc[1][0]+=a.y*b.x; acc[1][1]+=a.y*b.y; acc[1][2]+=a.y*b.z; acc[1][3]+=a.y*b.w;
            acc[2][0]+=a.z*b.x; acc[2][1]+=a.z*b.y; acc[2][2]+=a.z*b.z; acc[2][3]+=a.z*b.w;
            acc[3][0]+=a.w*b.x; acc[3][1]+=a.w*b.y; acc[3][2]+=a.w*b.z; acc[3][3]+=a.w*b.w;
        }
    }

    #pragma unroll
    for (int i = 0; i < 4; i++){
        int m = m0 + ty * 4 + i;
        int n = n0 + tx * 4;
        ushort4 o;
        o.x = f2bf(acc[i][0] + b1[n+0] + b2[n+0]);
        o.y = f2bf(acc[i][1] + b1[n+1] + b2[n+1]);
        o.z = f2bf(acc[i][2] + b1[n+2] + b2[n+2]);
        o.w = f2bf(acc[i][3] + b1[n+3] + b2[n+3]);
        *(ushort4*)(Xo + (size_t)m * 1024 + n) = o;
    }
}

// ---------- K2: persistent MFMA LSTM ----------
// Grid: 16 WGs (cooperative). wg = dir*8 + g. WG g owns h rows [g*32, g*32+32).
// Each WG: 256 threads = 4 waves. wave w: hg = w&1 (hrow half), mt = w>>1 (batch tile).
// Weight fragments (4 gates x 8 k-steps, 16B each) live in VGPRs for all 256 steps.
// Per step: gates[32b x 32h] = h[32x256] @ Wslice^T via mfma_f32_16x16x32_bf16,
// combine in-register (C layout: col=lane&15 -> hrow, row=(lane>>4)*4+reg -> batch),
// write h slice to HS, fence, flag; spin on prev-step flags at loop head.
__global__ __launch_bounds__(256, 1) void k2_lstm(
    const u16* __restrict__ X, const u16* __restrict__ wsw,
    const float* __restrict__ h0, const float* __restrict__ c0,
    u16* __restrict__ HS, int* __restrict__ flags){

    int wg = blockIdx.x;
    int dir = wg >> 3;
    int g = wg & 7;
    int tid = threadIdx.x;
    int w = tid >> 6, l = tid & 63;
    int hg = w & 1, mt = w >> 1;
    int lr = l & 15, lk = l >> 4;

    __shared__ __align__(16) u16 hl[32 * 264];   // h tile [32][264] bf16, +8 pad

    const u16* Wd = wsw + (size_t)dir * 262144;
    const u16* Xb = X + (size_t)dir * 8192 * 1024;

    int hrow = g * 32 + hg * 16 + lr;            // global h row this lane owns

    // --- load weight fragments into registers (loop-invariant) ---
    bf16x8 wf[4][8];
    #pragma unroll
    for (int gate = 0; gate < 4; gate++){
        const u16* wr_ = Wd + (size_t)(gate * 256 + hrow) * 256 + lk * 8;
        #pragma unroll
        for (int kk = 0; kk < 8; kk++)
            wf[gate][kk] = *(const bf16x8*)(wr_ + kk * 32);
    }

    // --- c state: 4 batches per lane ---
    float cst[4];
    #pragma unroll
    for (int r = 0; r < 4; r++){
        int b = mt * 16 + lk * 4 + r;
        cst[r] = c0[(dir * 32 + b) * 256 + hrow];
    }

    for (int s = 0; s < 256; s++){
        int tt = dir ? (255 - s) : s;

        if (s > 0){
            if (tid == 0){
                while (__hip_atomic_load(&flags[dir * 256 + (s - 1)],
                                         __ATOMIC_ACQUIRE, __HIP_MEMORY_SCOPE_AGENT) < 8)
                    __builtin_amdgcn_s_sleep(2);
            }
            __syncthreads();
        }

        // --- stage h_{t-1} (all 32 batches x 256) into LDS ---
        int tp = dir ? (tt + 1) : (tt - 1);
        #pragma unroll
        for (int i = 0; i < 4; i++){
            int chunk = tid * 4 + i;               // 0..1023, 8 elems each
            int b = chunk >> 5, col = (chunk & 31) * 8;
            bf16x8 v;
            if (s == 0){
                const float* src = h0 + (dir * 32 + b) * 256 + col;
                #pragma unroll
                for (int j = 0; j < 8; j++) v[j] = (__bf16)src[j];
            } else {
                v = *(const bf16x8*)(HS + ((size_t)(dir * 32 + b) * 256 + tp) * 256 + col);
            }
            *(bf16x8*)&hl[b * 264 + col] = v;
        }

        // --- X (input-projection gates) scalar loads, independent of LDS ---
        float xv[4][4];
        const u16* Xt = Xb + (size_t)tt * 1024 + hrow;
        #pragma unroll
        for (int gate = 0; gate < 4; gate++)
            #pragma unroll
            for (int r = 0; r < 4; r++){
                int b = mt * 16 + lk * 4 + r;
                xv[gate][r] = bf2f(Xt[(size_t)b * 262144 + gate * 256]);
            }

        __syncthreads();

        // --- A fragments from LDS ---
        bf16x8 af[8];
        #pragma unroll
        for (int kk = 0; kk < 8; kk++)
            af[kk] = *(const bf16x8*)&hl[(mt * 16 + lr) * 264 + kk * 32 + lk * 8];

        f32x4 acc[4];
        #pragma unroll
        for (int gate = 0; gate < 4; gate++) acc[gate] = (f32x4){0.f, 0.f, 0.f, 0.f};

        #pragma unroll
        for (int kk = 0; kk < 8; kk++)
            #pragma unroll
            for (int gate = 0; gate < 4; gate++)
                acc[gate] = __builtin_amdgcn_mfma_f32_16x16x32_bf16(
                    af[kk], wf[gate][kk], acc[gate], 0, 0, 0);

        // --- combine: lane has (4 batches) x (1 hrow) x 4 gates ---
        #pragma unroll
        for (int r = 0; r < 4; r++){
            float gi = sigm(acc[0][r] + xv[0][r]);
            float gf = sigm(acc[1][r] + xv[1][r]);
            float gg = tanh_(acc[2][r] + xv[2][r]);
            float go = sigm(acc[3][r] + xv[3][r]);
            cst[r] = gf * cst[r] + gi * gg;
            float h = go * tanh_(cst[r]);
            int b = mt * 16 + lk * 4 + r;
            HS[((size_t)(dir * 32 + b) * 256 + tt) * 256 + hrow] = f2bf(h);
        }

        __threadfence();
        __syncthreads();
        if (tid == 0) atomicAdd(&flags[dir * 256 + s], 1);
    }
}

// ---------- K3: feats = concat(fwd,bwd) @ W_out^T + b_out ----------
__global__ __launch_bounds__(192) void k3_feats(
    const u16* __restrict__ HS, const float* __restrict__ Wout,
    const float* __restrict__ bout, float* __restrict__ feats){
    int bt = blockIdx.x;            // b*256 + t
    int b = bt >> 8, t = bt & 255;
    __shared__ float hcat[512];
    __shared__ float part[12][16];
    int tid = threadIdx.x;

    for (int i = tid; i < 512; i += 192){
        int d = i >> 8, k = i & 255;
        hcat[i] = bf2f(HS[((size_t)(d * 32 + b) * 256 + t) * 256 + k]);
    }
    __syncthreads();

    int n = tid >> 4, p = tid & 15;     // n 0..11, p 0..15
    float s = 0.0f;
    const float* wr = Wout + (size_t)n * 512 + p * 32;
    #pragma unroll
    for (int e = 0; e < 32; e++) s += hcat[p * 32 + e] * wr[e];
    part[n][p] = s;
    __syncthreads();

    if (tid < 12){
        float acc = bout[tid];
        #pragma unroll
        for (int p2 = 0; p2 < 16; p2++) acc += part[tid][p2];
        feats[(size_t)bt * 12 + tid] = acc;
    }
}

// ---------- K4: CRF forward (log Z) + gold score, per batch ----------
__global__ __launch_bounds__(192) void k4_crf(
    const float* __restrict__ feats, const float* __restrict__ trans,
    const int* __restrict__ tags, float* __restrict__ scores){
    int b = blockIdx.x;
    int tid = threadIdx.x;
    int i = tid >> 4, j = tid & 15;     // i 0..11, j 0..15 (j<12 active)
    bool act = (j < 12);

    __shared__ float fv[12];
    __shared__ float red[12];
    __shared__ float s_lz;
    __shared__ float gred[192];

    float tij = act ? trans[i * 12 + j] : NEG;
    if (tid < 12) fv[tid] = (tid == 0) ? 0.0f : NEG;   // START = idx 0
    __syncthreads();

    const float* fb = feats + (size_t)b * 256 * 12;

    for (int t = 0; t < 256; t++){
        float e = act ? (fv[j] + tij) : -3.0e38f;
        float m = e;
        #pragma unroll
        for (int off = 1; off < 16; off <<= 1) m = fmaxf(m, __shfl_xor(m, off, 16));
        float ex = act ? __expf(e - m) : 0.0f;
        float ss = ex;
        #pragma unroll
        for (int off = 1; off < 16; off <<= 1) ss += __shfl_xor(ss, off, 16);
        if (j == 0) red[i] = fb[t * 12 + i] + m + __logf(ss);
        __syncthreads();
        if (tid < 12) fv[tid] = red[tid];
        __syncthreads();
    }

    if (i == 0){
        float e = (j < 12) ? (fv[j] + trans[12 + j]) : -3.0e38f;
        float m = e;
        #pragma unroll
        for (int off = 1; off < 16; off <<= 1) m = fmaxf(m, __shfl_xor(m, off, 16));
        float ex = (j < 12) ? __expf(e - m) : 0.0f;
        float ss = ex;
        #pragma unroll
        for (int off = 1; off < 16; off <<= 1) ss += __shfl_xor(ss, off, 16);
        if (j == 0) s_lz = m + __logf(ss);
    }
    __syncthreads();

    const int* tg = tags + b * 256;
    float gsum = 0.0f;
    for (int t = tid; t < 256; t += 192){
        int cur = tg[t];
        int prev = (t == 0) ? 0 : tg[t - 1];
        gsum += fb[t * 12 + cur] + trans[cur * 12 + prev];
    }
    gred[tid] = gsum;
    __syncthreads();
    if (tid == 0){
        float gg = 0.0f;
        for (int k = 0; k < 192; k++) gg += gred[k];
        gg += trans[12 + tg[255]];           // trans[STOP][last]
        scores[b] = s_lz - gg;
    }
}

// ---------- K5: final reduce over batches ----------
__global__ void k5_final(const float* __restrict__ scores, float* __restrict__ out){
    int t = threadIdx.x;
    float v = scores[t];
    #pragma unroll
    for (int off = 16; off; off >>= 1) v += __shfl_xor(v, off, 32);
    if (t == 0) out[0] = v;
}

// ---------- launch ----------
extern "C" void kernel_launch(void* const* d_in, const int* in_sizes, int n_in,
                              void* d_out, int out_size, void* d_ws, size_t ws_size,
                              hipStream_t stream){
    const int*   sent  = (const int*)d_in[0];
    const int*   tags  = (const int*)d_in[1];
    const float* emb   = (const float*)d_in[3];
    const float* Wih_f = (const float*)d_in[4];
    const float* Whh_f = (const float*)d_in[5];
    const float* bih_f = (const float*)d_in[6];
    const float* bhh_f = (const float*)d_in[7];
    const float* Wih_b = (const float*)d_in[8];
    const float* Whh_b = (const float*)d_in[9];
    const float* bih_b = (const float*)d_in[10];
    const float* bhh_b = (const float*)d_in[11];
    const float* Wout  = (const float*)d_in[12];
    const float* bout  = (const float*)d_in[13];
    const float* trans = (const float*)d_in[14];
    const float* h0    = (const float*)d_in[15];
    const float* c0    = (const float*)d_in[16];

    char* ws = (char*)d_ws;
    u16*   X      = (u16*)(ws);                    // 2*8192*1024 bf16 = 32 MB
    u16*   HS     = (u16*)(ws + 33554432);         // 2*32*256*256 bf16 = 8 MB
    float* FEATS  = (float*)(ws + 41943040);       // 32*256*12 f32
    u16*   WSW    = (u16*)(ws + 42336256);         // 2*1024*256 bf16 = 1 MB
    float* SCORES = (float*)(ws + 43384832);       // 32 f32
    int*   FLAGS  = (int*)(ws + 43384960);         // 512 ints

    hipLaunchKernelGGL(k0_convert, dim3(2048), dim3(256), 0, stream, Whh_f, Whh_b, WSW);
    hipLaunchKernelGGL(k1_inproj, dim3(128, 16, 2), dim3(256), 0, stream,
                       sent, emb, Wih_f, bih_f, bhh_f, Wih_b, bih_b, bhh_b, X);
    hipLaunchKernelGGL(k_zero, dim3(1), dim3(512), 0, stream, FLAGS);

    {
        const u16* Xc = X; const u16* Wc = WSW; u16* HSc = HS; int* Fc = FLAGS;
        const float* h0c = h0; const float* c0c = c0;
        void* kargs[] = { (void*)&Xc, (void*)&Wc, (void*)&h0c, (void*)&c0c,
                          (void*)&HSc, (void*)&Fc };
        hipLaunchCooperativeKernel((const void*)k2_lstm, dim3(16), dim3(256),
                                   kargs, 0, stream);
    }

    hipLaunchKernelGGL(k3_feats, dim3(8192), dim3(192), 0, stream, HS, Wout, bout, FEATS);
    hipLaunchKernelGGL(k4_crf, dim3(32), dim3(192), 0, stream, FEATS, trans, tags, SCORES);
    hipLaunchKernelGGL(k5_final, dim3(1), dim3(32), 0, stream, SCORES, (float*)d_out);
}

// Round 3
// 1245.749 us; speedup vs baseline: 3.1159x; 1.1032x over previous
//
#include <hip/hip_runtime.h>
#include <hip/hip_bf16.h>

typedef unsigned int u32;
typedef unsigned short u16;
typedef unsigned char u8;

typedef __attribute__((ext_vector_type(4))) float f32x4;

#define NEG (-10000.0f)
#define WSCALE 16.0f
#define WSCALE_INV 0.0625f

// ---------- helpers ----------
__device__ __forceinline__ float bf2f(u16 x){ return __uint_as_float(((u32)x) << 16); }
__device__ __forceinline__ u16 f2bf(float f){
    u32 u = __float_as_uint(f);
    u32 r = (u + 0x7fffu + ((u >> 16) & 1u)) >> 16;   // RNE
    return (u16)r;
}
__device__ __forceinline__ float sigm(float x){ return 1.0f / (1.0f + __expf(-x)); }
__device__ __forceinline__ float tanh_(float x){
    float e = __expf(2.0f * x);
    return 1.0f - 2.0f / (e + 1.0f);
}

// ---------- K0: W_hh f32 -> fp8 e4m3 (x16 scale), layout [dir][1024][256] ----------
__global__ void k0_convert(const float* __restrict__ Whh_f,
                           const float* __restrict__ Whh_b,
                           u32* __restrict__ w8){
    int gid = blockIdx.x * blockDim.x + threadIdx.x;   // 4 elems each
    if (gid >= 131072) return;
    int idx = gid * 4;
    int dir = idx >> 18;
    int off = idx & 0x3FFFF;
    const float* W = dir ? Whh_b : Whh_f;
    int pk = __builtin_amdgcn_cvt_pk_fp8_f32(W[off] * WSCALE, W[off + 1] * WSCALE, 0, false);
    pk = __builtin_amdgcn_cvt_pk_fp8_f32(W[off + 2] * WSCALE, W[off + 3] * WSCALE, pk, true);
    w8[gid] = (u32)pk;
}

// ---------- K1: input projection GEMM, fp32 tiled, X = emb@W_ih^T + b_ih + b_hh (bf16 out) ----------
__global__ __launch_bounds__(256) void k1_inproj(
    const int* __restrict__ sent, const float* __restrict__ emb,
    const float* __restrict__ Wih_f, const float* __restrict__ bih_f, const float* __restrict__ bhh_f,
    const float* __restrict__ Wih_b, const float* __restrict__ bih_b, const float* __restrict__ bhh_b,
    u16* __restrict__ X){
    int dir = blockIdx.z;
    const float* W  = dir ? Wih_b : Wih_f;
    const float* b1 = dir ? bih_b : bih_f;
    const float* b2 = dir ? bhh_b : bhh_f;
    u16* Xo = X + (size_t)dir * 8192 * 1024;

    __shared__ float As[16][68];
    __shared__ float Bs[16][68];

    int tid = threadIdx.x;
    int tx = tid & 15, ty = tid >> 4;
    int m0 = blockIdx.x * 64, n0 = blockIdx.y * 64;

    int lm = tid >> 2;        // 0..63
    int lk = (tid & 3) * 4;   // 0,4,8,12
    int sid = sent[m0 + lm];
    const float* arow = emb + (size_t)sid * 256;
    const float* brow = W + (size_t)(n0 + lm) * 256;

    float acc[4][4] = {};

    for (int k0 = 0; k0 < 256; k0 += 16){
        float4 av = *(const float4*)(arow + k0 + lk);
        float4 bv = *(const float4*)(brow + k0 + lk);
        __syncthreads();
        As[lk+0][lm]=av.x; As[lk+1][lm]=av.y; As[lk+2][lm]=av.z; As[lk+3][lm]=av.w;
        Bs[lk+0][lm]=bv.x; Bs[lk+1][lm]=bv.y; Bs[lk+2][lm]=bv.z; Bs[lk+3][lm]=bv.w;
        __syncthreads();
        #pragma unroll
        for (int kk = 0; kk < 16; kk++){
            float4 a = *(const float4*)&As[kk][ty * 4];
            float4 b = *(const float4*)&Bs[kk][tx * 4];
            acc[0][0]+=a.x*b.x; acc[0][1]+=a.x*b.y; acc[0][2]+=a.x*b.z; acc[0][3]+=a.x*b.w;
            acc[1][0]+=a.y*b.x; acc[1][1]+=a.y*b.y; acc[1][2]+=a.y*b.z; acc[1][3]+=a.y*b.w;
            acc[2][0]+=a.z*b.x; acc[2][1]+=a.z*b.y; acc[2][2]+=a.z*b.z; acc[2][3]+=a.z*b.w;
            acc[3][0]+=a.w*b.x; acc[3][1]+=a.w*b.y; acc[3][2]+=a.w*b.z; acc[3][3]+=a.w*b.w;
        }
    }

    #pragma unroll
    for (int i = 0; i < 4; i++){
        int m = m0 + ty * 4 + i;
        int n = n0 + tx * 4;
        ushort4 o;
        o.x = f2bf(acc[i][0] + b1[n+0] + b2[n+0]);
        o.y = f2bf(acc[i][1] + b1[n+1] + b2[n+1]);
        o.z = f2bf(acc[i][2] + b1[n+2] + b2[n+2]);
        o.w = f2bf(acc[i][3] + b1[n+3] + b2[n+3]);
        *(ushort4*)(Xo + (size_t)m * 1024 + n) = o;
    }
}

// ---------- K2: self-contained fp8 MFMA LSTM ----------
// 4 WGs: wg = dir*2 + half. Each WG owns 16 batches (bbase = half*16) and the FULL
// weight matrix (fp8, 128 VGPRs/wave across 8 waves). h recurrence lives entirely in
// LDS (fp8, double-buffered) -> one __syncthreads per step, zero global sync.
// Wave w owns hidden [w*32, w*32+32): lane lr handles hid0 = w*32+2*lr and hid0+1
// (interleaved N-tiles so per-lane hiddens are adjacent -> u32 X loads / HS stores).
__global__ __launch_bounds__(512, 2) void k2_lstm(
    const u16* __restrict__ X, const u8* __restrict__ w8,
    const float* __restrict__ h0, const float* __restrict__ c0,
    u16* __restrict__ HS){

    int wg = blockIdx.x;
    int dir = wg >> 1, half = wg & 1;
    int tid = threadIdx.x;
    int w = tid >> 6, l = tid & 63;
    int lr = l & 15, lk = l >> 4;
    int bbase = half * 16;

    __shared__ __align__(16) u8 hl[2][16][272];     // [buf][batch][hid fp8 +16B pad]

    const u8* Wd = w8 + (size_t)dir * 262144;
    const u16* Xd = X + (size_t)dir * 8192 * 1024;

    int hid0 = w * 32 + 2 * lr;

    // --- weight fragments: B[k][n] = W[n-th gate row][k], n-tiles interleaved ---
    long wf[4][2][8];
    #pragma unroll
    for (int g = 0; g < 4; g++)
        #pragma unroll
        for (int t = 0; t < 2; t++)
            #pragma unroll
            for (int kk = 0; kk < 8; kk++)
                wf[g][t][kk] = *(const long*)(Wd + (size_t)(g * 256 + hid0 + t) * 256 + kk * 32 + lk * 8);

    // --- c state: 2 hiddens x 4 batches per lane ---
    float cst[2][4];
    #pragma unroll
    for (int t = 0; t < 2; t++)
        #pragma unroll
        for (int r = 0; r < 4; r++)
            cst[t][r] = c0[(size_t)(dir * 32 + bbase + lk * 4 + r) * 256 + hid0 + t];

    // --- stage h0 (f32 -> fp8) into hl[0] ---
    {
        int row = tid >> 5;            // 0..15
        int col = (tid & 31) * 8;      // 0..248
        const float* src = h0 + (size_t)(dir * 32 + bbase + row) * 256 + col;
        int p0 = __builtin_amdgcn_cvt_pk_fp8_f32(src[0], src[1], 0, false);
        p0 = __builtin_amdgcn_cvt_pk_fp8_f32(src[2], src[3], p0, true);
        int p1 = __builtin_amdgcn_cvt_pk_fp8_f32(src[4], src[5], 0, false);
        p1 = __builtin_amdgcn_cvt_pk_fp8_f32(src[6], src[7], p1, true);
        u32* dst = (u32*)&hl[0][row][col];
        dst[0] = (u32)p0; dst[1] = (u32)p1;
    }
    __syncthreads();

    for (int s = 0; s < 256; s++){
        int tt = dir ? (255 - s) : s;
        int cur = s & 1, nxt = cur ^ 1;

        // --- X for this step: 16 u32 loads (bf16 pair per (gate,batch)), issued early ---
        u32 xp[4][4];
        #pragma unroll
        for (int g = 0; g < 4; g++)
            #pragma unroll
            for (int r = 0; r < 4; r++)
                xp[g][r] = *(const u32*)(Xd + (size_t)(bbase + lk * 4 + r) * 262144
                                           + (size_t)tt * 1024 + g * 256 + hid0);

        // --- A fragments (h_{t-1}, fp8) from LDS ---
        long af[8];
        #pragma unroll
        for (int kk = 0; kk < 8; kk++)
            af[kk] = *(const long*)&hl[cur][lr][kk * 32 + lk * 8];

        f32x4 acc[4][2];
        #pragma unroll
        for (int g = 0; g < 4; g++)
            #pragma unroll
            for (int t = 0; t < 2; t++)
                acc[g][t] = (f32x4){0.f, 0.f, 0.f, 0.f};

        #pragma unroll
        for (int kk = 0; kk < 8; kk++)
            #pragma unroll
            for (int g = 0; g < 4; g++)
                #pragma unroll
                for (int t = 0; t < 2; t++)
                    acc[g][t] = __builtin_amdgcn_mfma_f32_16x16x32_fp8_fp8(
                        af[kk], wf[g][t][kk], acc[g][t], 0, 0, 0);

        // --- combine: lane has (2 hiddens) x (4 batches) x 4 gates ---
        #pragma unroll
        for (int r = 0; r < 4; r++){
            float hh[2];
            #pragma unroll
            for (int t = 0; t < 2; t++){
                float xi = t ? bf2f((u16)(xp[0][r] >> 16)) : bf2f((u16)(xp[0][r] & 0xFFFF));
                float xf = t ? bf2f((u16)(xp[1][r] >> 16)) : bf2f((u16)(xp[1][r] & 0xFFFF));
                float xg = t ? bf2f((u16)(xp[2][r] >> 16)) : bf2f((u16)(xp[2][r] & 0xFFFF));
                float xo = t ? bf2f((u16)(xp[3][r] >> 16)) : bf2f((u16)(xp[3][r] & 0xFFFF));
                float gi = sigm(acc[0][t][r] * WSCALE_INV + xi);
                float gf = sigm(acc[1][t][r] * WSCALE_INV + xf);
                float gg = tanh_(acc[2][t][r] * WSCALE_INV + xg);
                float go = sigm(acc[3][t][r] * WSCALE_INV + xo);
                cst[t][r] = gf * cst[t][r] + gi * gg;
                hh[t] = go * tanh_(cst[t][r]);
            }
            int brow = lk * 4 + r;                       // batch within WG
            int pk = __builtin_amdgcn_cvt_pk_fp8_f32(hh[0], hh[1], 0, false);
            *(u16*)&hl[nxt][brow][hid0] = (u16)pk;
            u32 hw = (u32)f2bf(hh[0]) | ((u32)f2bf(hh[1]) << 16);
            *(u32*)&HS[((size_t)(dir * 32 + bbase + brow) * 256 + tt) * 256 + hid0] = hw;
        }

        __syncthreads();
    }
}

// ---------- K3: feats = concat(fwd,bwd) @ W_out^T + b_out ----------
__global__ __launch_bounds__(192) void k3_feats(
    const u16* __restrict__ HS, const float* __restrict__ Wout,
    const float* __restrict__ bout, float* __restrict__ feats){
    int bt = blockIdx.x;            // b*256 + t
    int b = bt >> 8, t = bt & 255;
    __shared__ float hcat[512];
    __shared__ float part[12][16];
    int tid = threadIdx.x;

    for (int i = tid; i < 512; i += 192){
        int d = i >> 8, k = i & 255;
        hcat[i] = bf2f(HS[((size_t)(d * 32 + b) * 256 + t) * 256 + k]);
    }
    __syncthreads();

    int n = tid >> 4, p = tid & 15;     // n 0..11, p 0..15
    float s = 0.0f;
    const float* wr = Wout + (size_t)n * 512 + p * 32;
    #pragma unroll
    for (int e = 0; e < 32; e++) s += hcat[p * 32 + e] * wr[e];
    part[n][p] = s;
    __syncthreads();

    if (tid < 12){
        float acc = bout[tid];
        #pragma unroll
        for (int p2 = 0; p2 < 16; p2++) acc += part[tid][p2];
        feats[(size_t)bt * 12 + tid] = acc;
    }
}

// ---------- K4: CRF forward (log Z) + gold score, per batch ----------
__global__ __launch_bounds__(192) void k4_crf(
    const float* __restrict__ feats, const float* __restrict__ trans,
    const int* __restrict__ tags, float* __restrict__ scores){
    int b = blockIdx.x;
    int tid = threadIdx.x;
    int i = tid >> 4, j = tid & 15;     // i 0..11, j 0..15 (j<12 active)
    bool act = (j < 12);

    __shared__ float fv[12];
    __shared__ float red[12];
    __shared__ float s_lz;
    __shared__ float gred[192];

    float tij = act ? trans[i * 12 + j] : NEG;
    if (tid < 12) fv[tid] = (tid == 0) ? 0.0f : NEG;   // START = idx 0
    __syncthreads();

    const float* fb = feats + (size_t)b * 256 * 12;

    for (int t = 0; t < 256; t++){
        float e = act ? (fv[j] + tij) : -3.0e38f;
        float m = e;
        #pragma unroll
        for (int off = 1; off < 16; off <<= 1) m = fmaxf(m, __shfl_xor(m, off, 16));
        float ex = act ? __expf(e - m) : 0.0f;
        float ss = ex;
        #pragma unroll
        for (int off = 1; off < 16; off <<= 1) ss += __shfl_xor(ss, off, 16);
        if (j == 0) red[i] = fb[t * 12 + i] + m + __logf(ss);
        __syncthreads();
        if (tid < 12) fv[tid] = red[tid];
        __syncthreads();
    }

    if (i == 0){
        float e = (j < 12) ? (fv[j] + trans[12 + j]) : -3.0e38f;
        float m = e;
        #pragma unroll
        for (int off = 1; off < 16; off <<= 1) m = fmaxf(m, __shfl_xor(m, off, 16));
        float ex = (j < 12) ? __expf(e - m) : 0.0f;
        float ss = ex;
        #pragma unroll
        for (int off = 1; off < 16; off <<= 1) ss += __shfl_xor(ss, off, 16);
        if (j == 0) s_lz = m + __logf(ss);
    }
    __syncthreads();

    const int* tg = tags + b * 256;
    float gsum = 0.0f;
    for (int t = tid; t < 256; t += 192){
        int cur = tg[t];
        int prev = (t == 0) ? 0 : tg[t - 1];
        gsum += fb[t * 12 + cur] + trans[cur * 12 + prev];
    }
    gred[tid] = gsum;
    __syncthreads();
    if (tid == 0){
        float gg = 0.0f;
        for (int k = 0; k < 192; k++) gg += gred[k];
        gg += trans[12 + tg[255]];           // trans[STOP][last]
        scores[b] = s_lz - gg;
    }
}

// ---------- K5: final reduce over batches ----------
__global__ void k5_final(const float* __restrict__ scores, float* __restrict__ out){
    int t = threadIdx.x;
    float v = scores[t];
    #pragma unroll
    for (int off = 16; off; off >>= 1) v += __shfl_xor(v, off, 32);
    if (t == 0) out[0] = v;
}

// ---------- launch ----------
extern "C" void kernel_launch(void* const* d_in, const int* in_sizes, int n_in,
                              void* d_out, int out_size, void* d_ws, size_t ws_size,
                              hipStream_t stream){
    const int*   sent  = (const int*)d_in[0];
    const int*   tags  = (const int*)d_in[1];
    const float* emb   = (const float*)d_in[3];
    const float* Wih_f = (const float*)d_in[4];
    const float* Whh_f = (const float*)d_in[5];
    const float* bih_f = (const float*)d_in[6];
    const float* bhh_f = (const float*)d_in[7];
    const float* Wih_b = (const float*)d_in[8];
    const float* Whh_b = (const float*)d_in[9];
    const float* bih_b = (const float*)d_in[10];
    const float* bhh_b = (const float*)d_in[11];
    const float* Wout  = (const float*)d_in[12];
    const float* bout  = (const float*)d_in[13];
    const float* trans = (const float*)d_in[14];
    const float* h0    = (const float*)d_in[15];
    const float* c0    = (const float*)d_in[16];

    char* ws = (char*)d_ws;
    u16*   X      = (u16*)(ws);                    // 2*8192*1024 bf16 = 32 MB
    u16*   HS     = (u16*)(ws + 33554432);         // 2*32*256*256 bf16 = 8 MB
    float* FEATS  = (float*)(ws + 41943040);       // 32*256*12 f32
    u8*    W8     = (u8*)(ws + 42336256);          // 2*1024*256 fp8 = 512 KB
    float* SCORES = (float*)(ws + 43384832);       // 32 f32

    hipLaunchKernelGGL(k0_convert, dim3(512), dim3(256), 0, stream, Whh_f, Whh_b, (u32*)W8);
    hipLaunchKernelGGL(k1_inproj, dim3(128, 16, 2), dim3(256), 0, stream,
                       sent, emb, Wih_f, bih_f, bhh_f, Wih_b, bih_b, bhh_b, X);
    hipLaunchKernelGGL(k2_lstm, dim3(4), dim3(512), 0, stream, X, W8, h0, c0, HS);
    hipLaunchKernelGGL(k3_feats, dim3(8192), dim3(192), 0, stream, HS, Wout, bout, FEATS);
    hipLaunchKernelGGL(k4_crf, dim3(32), dim3(192), 0, stream, FEATS, trans, tags, SCORES);
    hipLaunchKernelGGL(k5_final, dim3(1), dim3(32), 0, stream, SCORES, (float*)d_out);
}

// Round 4
// 781.765 us; speedup vs baseline: 4.9651x; 1.5935x over previous
//
#include <hip/hip_runtime.h>
#include <hip/hip_bf16.h>

typedef unsigned int u32;
typedef unsigned short u16;
typedef unsigned char u8;

typedef __attribute__((ext_vector_type(4))) float f32x4;
typedef __attribute__((ext_vector_type(8))) int i32x8;

#define NEG (-10000.0f)
#define WSCALE 16.0f
#define WSCALE_INV 0.0625f

// ---------- helpers ----------
__device__ __forceinline__ float bf2f(u16 x){ return __uint_as_float(((u32)x) << 16); }
__device__ __forceinline__ u16 f2bf(float f){
    u32 u = __float_as_uint(f);
    u32 r = (u + 0x7fffu + ((u >> 16) & 1u)) >> 16;   // RNE
    return (u16)r;
}
// fast sigmoid/tanh: v_exp + v_rcp (no IEEE divide expansion)
__device__ __forceinline__ float sigm(float x){
    float e = __expf(-x);
    return __builtin_amdgcn_rcpf(1.0f + e);
}
__device__ __forceinline__ float tanh_(float x){
    float e = __expf(2.0f * x);
    return 1.0f - 2.0f * __builtin_amdgcn_rcpf(e + 1.0f);
}

// ---------- K0: W_hh f32 -> fp8 e4m3 (x16 scale), layout [dir][1024][256] ----------
__global__ void k0_convert(const float* __restrict__ Whh_f,
                           const float* __restrict__ Whh_b,
                           u32* __restrict__ w8){
    int gid = blockIdx.x * blockDim.x + threadIdx.x;   // 4 elems each
    if (gid >= 131072) return;
    int idx = gid * 4;
    int dir = idx >> 18;
    int off = idx & 0x3FFFF;
    const float* W = dir ? Whh_b : Whh_f;
    int pk = __builtin_amdgcn_cvt_pk_fp8_f32(W[off] * WSCALE, W[off + 1] * WSCALE, 0, false);
    pk = __builtin_amdgcn_cvt_pk_fp8_f32(W[off + 2] * WSCALE, W[off + 3] * WSCALE, pk, true);
    w8[gid] = (u32)pk;
}

// ---------- K1: input projection GEMM, fp32 tiled, X = emb@W_ih^T + b_ih + b_hh (bf16 out) ----------
__global__ __launch_bounds__(256) void k1_inproj(
    const int* __restrict__ sent, const float* __restrict__ emb,
    const float* __restrict__ Wih_f, const float* __restrict__ bih_f, const float* __restrict__ bhh_f,
    const float* __restrict__ Wih_b, const float* __restrict__ bih_b, const float* __restrict__ bhh_b,
    u16* __restrict__ X){
    int dir = blockIdx.z;
    const float* W  = dir ? Wih_b : Wih_f;
    const float* b1 = dir ? bih_b : bih_f;
    const float* b2 = dir ? bhh_b : bhh_f;
    u16* Xo = X + (size_t)dir * 8192 * 1024;

    __shared__ float As[16][68];
    __shared__ float Bs[16][68];

    int tid = threadIdx.x;
    int tx = tid & 15, ty = tid >> 4;
    int m0 = blockIdx.x * 64, n0 = blockIdx.y * 64;

    int lm = tid >> 2;        // 0..63
    int lk = (tid & 3) * 4;   // 0,4,8,12
    int sid = sent[m0 + lm];
    const float* arow = emb + (size_t)sid * 256;
    const float* brow = W + (size_t)(n0 + lm) * 256;

    float acc[4][4] = {};

    for (int k0 = 0; k0 < 256; k0 += 16){
        float4 av = *(const float4*)(arow + k0 + lk);
        float4 bv = *(const float4*)(brow + k0 + lk);
        __syncthreads();
        As[lk+0][lm]=av.x; As[lk+1][lm]=av.y; As[lk+2][lm]=av.z; As[lk+3][lm]=av.w;
        Bs[lk+0][lm]=bv.x; Bs[lk+1][lm]=bv.y; Bs[lk+2][lm]=bv.z; Bs[lk+3][lm]=bv.w;
        __syncthreads();
        #pragma unroll
        for (int kk = 0; kk < 16; kk++){
            float4 a = *(const float4*)&As[kk][ty * 4];
            float4 b = *(const float4*)&Bs[kk][tx * 4];
            acc[0][0]+=a.x*b.x; acc[0][1]+=a.x*b.y; acc[0][2]+=a.x*b.z; acc[0][3]+=a.x*b.w;
            acc[1][0]+=a.y*b.x; acc[1][1]+=a.y*b.y; acc[1][2]+=a.y*b.z; acc[1][3]+=a.y*b.w;
            acc[2][0]+=a.z*b.x; acc[2][1]+=a.z*b.y; acc[2][2]+=a.z*b.z; acc[2][3]+=a.z*b.w;
            acc[3][0]+=a.w*b.x; acc[3][1]+=a.w*b.y; acc[3][2]+=a.w*b.z; acc[3][3]+=a.w*b.w;
        }
    }

    #pragma unroll
    for (int i = 0; i < 4; i++){
        int m = m0 + ty * 4 + i;
        int n = n0 + tx * 4;
        ushort4 o;
        o.x = f2bf(acc[i][0] + b1[n+0] + b2[n+0]);
        o.y = f2bf(acc[i][1] + b1[n+1] + b2[n+1]);
        o.z = f2bf(acc[i][2] + b1[n+2] + b2[n+2]);
        o.w = f2bf(acc[i][3] + b1[n+3] + b2[n+3]);
        *(ushort4*)(Xo + (size_t)m * 1024 + n) = o;
    }
}

// ---------- K2: self-contained MX-fp8 (K=128) MFMA LSTM ----------
// 4 WGs: wg = dir*2 + half, 16 batches each, full weights in VGPRs (128/wave).
// Per step per wave: 16 mfma_scale_f32_16x16x128_f8f6f4 (unit e8m0 scales).
// A (h) and B (W) both packed with position->k map: k = lk*32 + byte, window ko*128.
__global__ __launch_bounds__(512, 2) void k2_lstm(
    const u16* __restrict__ X, const u8* __restrict__ w8,
    const float* __restrict__ h0, const float* __restrict__ c0,
    u16* __restrict__ HS){

    int wg = blockIdx.x;
    int dir = wg >> 1, half = wg & 1;
    int tid = threadIdx.x;
    int w = tid >> 6, l = tid & 63;
    int lr = l & 15, lk = l >> 4;
    int bbase = half * 16;

    __shared__ __align__(16) u8 hl[2][16][272];     // [buf][batch][hid fp8 +16B pad]

    const u8* Wd = w8 + (size_t)dir * 262144;
    const u16* Xd = X + (size_t)dir * 8192 * 1024;

    int hid0 = w * 32 + 2 * lr;     // interleaved N-tiles: tile t covers hiddens == t (mod 2)

    // --- weight fragments: wf[g][t][ko] = 32B of W[(g*256+hid0+t)][ko*128 + lk*32 ..] ---
    i32x8 wf[4][2][2];
    #pragma unroll
    for (int g = 0; g < 4; g++)
        #pragma unroll
        for (int t = 0; t < 2; t++)
            #pragma unroll
            for (int ko = 0; ko < 2; ko++)
                wf[g][t][ko] = *(const i32x8*)(Wd + (size_t)(g * 256 + hid0 + t) * 256
                                               + ko * 128 + lk * 32);

    // --- c state: 2 hiddens x 4 batches per lane ---
    float cst[2][4];
    #pragma unroll
    for (int t = 0; t < 2; t++)
        #pragma unroll
        for (int r = 0; r < 4; r++)
            cst[t][r] = c0[(size_t)(dir * 32 + bbase + lk * 4 + r) * 256 + hid0 + t];

    // --- hoisted base pointers (per r = batch sub-row) ---
    const u16* xb[4];
    u16* hsb[4];
    #pragma unroll
    for (int r = 0; r < 4; r++){
        xb[r]  = Xd + (size_t)(bbase + lk * 4 + r) * 262144 + hid0;
        hsb[r] = HS + (size_t)(dir * 32 + bbase + lk * 4 + r) * 65536 + hid0;
    }

    // --- stage h0 (f32 -> fp8) into hl[0] ---
    {
        int row = tid >> 5;            // 0..15
        int col = (tid & 31) * 8;      // 0..248
        const float* src = h0 + (size_t)(dir * 32 + bbase + row) * 256 + col;
        int p0 = __builtin_amdgcn_cvt_pk_fp8_f32(src[0], src[1], 0, false);
        p0 = __builtin_amdgcn_cvt_pk_fp8_f32(src[2], src[3], p0, true);
        int p1 = __builtin_amdgcn_cvt_pk_fp8_f32(src[4], src[5], 0, false);
        p1 = __builtin_amdgcn_cvt_pk_fp8_f32(src[6], src[7], p1, true);
        u32* dst = (u32*)&hl[0][row][col];
        dst[0] = (u32)p0; dst[1] = (u32)p1;
    }
    __syncthreads();

    for (int s = 0; s < 256; s++){
        int tt = dir ? (255 - s) : s;
        int cur = s & 1, nxt = cur ^ 1;
        int xoff = tt * 1024;

        // --- X loads: 4 addresses, 4 imm-offset u32 loads each ---
        u32 xp[4][4];      // [gate][r]
        #pragma unroll
        for (int r = 0; r < 4; r++){
            const u16* xr_ = xb[r] + xoff;
            #pragma unroll
            for (int g = 0; g < 4; g++)
                xp[g][r] = *(const u32*)(xr_ + g * 256);
        }

        // --- A fragments (h_{t-1}, fp8) from LDS: 2x 32B ---
        i32x8 af[2];
        #pragma unroll
        for (int ko = 0; ko < 2; ko++)
            af[ko] = *(const i32x8*)&hl[cur][lr][ko * 128 + lk * 32];

        f32x4 acc[4][2];
        #pragma unroll
        for (int g = 0; g < 4; g++)
            #pragma unroll
            for (int t = 0; t < 2; t++)
                acc[g][t] = (f32x4){0.f, 0.f, 0.f, 0.f};

        __builtin_amdgcn_s_setprio(1);
        #pragma unroll
        for (int ko = 0; ko < 2; ko++)
            #pragma unroll
            for (int g = 0; g < 4; g++)
                #pragma unroll
                for (int t = 0; t < 2; t++)
                    acc[g][t] = __builtin_amdgcn_mfma_scale_f32_16x16x128_f8f6f4(
                        af[ko], wf[g][t][ko], acc[g][t],
                        0, 0,                      // cbsz=fp8 e4m3 (A), blgp=fp8 e4m3 (B)
                        0, 0x7F7F7F7F,             // scale A = 1.0
                        0, 0x7F7F7F7F);            // scale B = 1.0
        __builtin_amdgcn_s_setprio(0);

        // --- combine: lane has (2 hiddens) x (4 batches) ---
        #pragma unroll
        for (int r = 0; r < 4; r++){
            float hh[2];
            #pragma unroll
            for (int t = 0; t < 2; t++){
                float xi = t ? __uint_as_float(xp[0][r] & 0xFFFF0000u)
                             : __uint_as_float(xp[0][r] << 16);
                float xf = t ? __uint_as_float(xp[1][r] & 0xFFFF0000u)
                             : __uint_as_float(xp[1][r] << 16);
                float xg = t ? __uint_as_float(xp[2][r] & 0xFFFF0000u)
                             : __uint_as_float(xp[2][r] << 16);
                float xo = t ? __uint_as_float(xp[3][r] & 0xFFFF0000u)
                             : __uint_as_float(xp[3][r] << 16);
                float gi = sigm(acc[0][t][r] * WSCALE_INV + xi);
                float gf = sigm(acc[1][t][r] * WSCALE_INV + xf);
                float gg = tanh_(acc[2][t][r] * WSCALE_INV + xg);
                float go = sigm(acc[3][t][r] * WSCALE_INV + xo);
                cst[t][r] = gf * cst[t][r] + gi * gg;
                hh[t] = go * tanh_(cst[t][r]);
            }
            int brow = lk * 4 + r;                       // batch within WG
            int pk = __builtin_amdgcn_cvt_pk_fp8_f32(hh[0], hh[1], 0, false);
            *(u16*)&hl[nxt][brow][hid0] = (u16)pk;
            u32 hw = (u32)f2bf(hh[0]) | ((u32)f2bf(hh[1]) << 16);
            *(u32*)(hsb[r] + tt * 256) = hw;
        }

        __syncthreads();
    }
}

// ---------- K3: feats = concat(fwd,bwd) @ W_out^T + b_out ----------
__global__ __launch_bounds__(192) void k3_feats(
    const u16* __restrict__ HS, const float* __restrict__ Wout,
    const float* __restrict__ bout, float* __restrict__ feats){
    int bt = blockIdx.x;            // b*256 + t
    int b = bt >> 8, t = bt & 255;
    __shared__ float hcat[512];
    __shared__ float part[12][16];
    int tid = threadIdx.x;

    for (int i = tid; i < 512; i += 192){
        int d = i >> 8, k = i & 255;
        hcat[i] = bf2f(HS[((size_t)(d * 32 + b) * 256 + t) * 256 + k]);
    }
    __syncthreads();

    int n = tid >> 4, p = tid & 15;     // n 0..11, p 0..15
    float s = 0.0f;
    const float* wr = Wout + (size_t)n * 512 + p * 32;
    #pragma unroll
    for (int e = 0; e < 32; e++) s += hcat[p * 32 + e] * wr[e];
    part[n][p] = s;
    __syncthreads();

    if (tid < 12){
        float acc = bout[tid];
        #pragma unroll
        for (int p2 = 0; p2 < 16; p2++) acc += part[tid][p2];
        feats[(size_t)bt * 12 + tid] = acc;
    }
}

// ---------- K4: CRF forward (log Z) + gold score, per batch ----------
__global__ __launch_bounds__(192) void k4_crf(
    const float* __restrict__ feats, const float* __restrict__ trans,
    const int* __restrict__ tags, float* __restrict__ scores){
    int b = blockIdx.x;
    int tid = threadIdx.x;
    int i = tid >> 4, j = tid & 15;     // i 0..11, j 0..15 (j<12 active)
    bool act = (j < 12);

    __shared__ float fv[12];
    __shared__ float red[12];
    __shared__ float s_lz;
    __shared__ float gred[192];

    float tij = act ? trans[i * 12 + j] : NEG;
    if (tid < 12) fv[tid] = (tid == 0) ? 0.0f : NEG;   // START = idx 0
    __syncthreads();

    const float* fb = feats + (size_t)b * 256 * 12;

    for (int t = 0; t < 256; t++){
        float e = act ? (fv[j] + tij) : -3.0e38f;
        float m = e;
        #pragma unroll
        for (int off = 1; off < 16; off <<= 1) m = fmaxf(m, __shfl_xor(m, off, 16));
        float ex = act ? __expf(e - m) : 0.0f;
        float ss = ex;
        #pragma unroll
        for (int off = 1; off < 16; off <<= 1) ss += __shfl_xor(ss, off, 16);
        if (j == 0) red[i] = fb[t * 12 + i] + m + __logf(ss);
        __syncthreads();
        if (tid < 12) fv[tid] = red[tid];
        __syncthreads();
    }

    if (i == 0){
        float e = (j < 12) ? (fv[j] + trans[12 + j]) : -3.0e38f;
        float m = e;
        #pragma unroll
        for (int off = 1; off < 16; off <<= 1) m = fmaxf(m, __shfl_xor(m, off, 16));
        float ex = (j < 12) ? __expf(e - m) : 0.0f;
        float ss = ex;
        #pragma unroll
        for (int off = 1; off < 16; off <<= 1) ss += __shfl_xor(ss, off, 16);
        if (j == 0) s_lz = m + __logf(ss);
    }
    __syncthreads();

    const int* tg = tags + b * 256;
    float gsum = 0.0f;
    for (int t = tid; t < 256; t += 192){
        int cur = tg[t];
        int prev = (t == 0) ? 0 : tg[t - 1];
        gsum += fb[t * 12 + cur] + trans[cur * 12 + prev];
    }
    gred[tid] = gsum;
    __syncthreads();
    if (tid == 0){
        float gg = 0.0f;
        for (int k = 0; k < 192; k++) gg += gred[k];
        gg += trans[12 + tg[255]];           // trans[STOP][last]
        scores[b] = s_lz - gg;
    }
}

// ---------- K5: final reduce over batches ----------
__global__ void k5_final(const float* __restrict__ scores, float* __restrict__ out){
    int t = threadIdx.x;
    float v = scores[t];
    #pragma unroll
    for (int off = 16; off; off >>= 1) v += __shfl_xor(v, off, 32);
    if (t == 0) out[0] = v;
}

// ---------- launch ----------
extern "C" void kernel_launch(void* const* d_in, const int* in_sizes, int n_in,
                              void* d_out, int out_size, void* d_ws, size_t ws_size,
                              hipStream_t stream){
    const int*   sent  = (const int*)d_in[0];
    const int*   tags  = (const int*)d_in[1];
    const float* emb   = (const float*)d_in[3];
    const float* Wih_f = (const float*)d_in[4];
    const float* Whh_f = (const float*)d_in[5];
    const float* bih_f = (const float*)d_in[6];
    const float* bhh_f = (const float*)d_in[7];
    const float* Wih_b = (const float*)d_in[8];
    const float* Whh_b = (const float*)d_in[9];
    const float* bih_b = (const float*)d_in[10];
    const float* bhh_b = (const float*)d_in[11];
    const float* Wout  = (const float*)d_in[12];
    const float* bout  = (const float*)d_in[13];
    const float* trans = (const float*)d_in[14];
    const float* h0    = (const float*)d_in[15];
    const float* c0    = (const float*)d_in[16];

    char* ws = (char*)d_ws;
    u16*   X      = (u16*)(ws);                    // 2*8192*1024 bf16 = 32 MB
    u16*   HS     = (u16*)(ws + 33554432);         // 2*32*256*256 bf16 = 8 MB
    float* FEATS  = (float*)(ws + 41943040);       // 32*256*12 f32
    u8*    W8     = (u8*)(ws + 42336256);          // 2*1024*256 fp8 = 512 KB
    float* SCORES = (float*)(ws + 43384832);       // 32 f32

    hipLaunchKernelGGL(k0_convert, dim3(512), dim3(256), 0, stream, Whh_f, Whh_b, (u32*)W8);
    hipLaunchKernelGGL(k1_inproj, dim3(128, 16, 2), dim3(256), 0, stream,
                       sent, emb, Wih_f, bih_f, bhh_f, Wih_b, bih_b, bhh_b, X);
    hipLaunchKernelGGL(k2_lstm, dim3(4), dim3(512), 0, stream, X, W8, h0, c0, HS);
    hipLaunchKernelGGL(k3_feats, dim3(8192), dim3(192), 0, stream, HS, Wout, bout, FEATS);
    hipLaunchKernelGGL(k4_crf, dim3(32), dim3(192), 0, stream, FEATS, trans, tags, SCORES);
    hipLaunchKernelGGL(k5_final, dim3(1), dim3(32), 0, stream, SCORES, (float*)d_out);
}